// Round 4
// baseline (104.807 us; speedup 1.0000x reference)
//
#include <hip/hip_runtime.h>

#define NCH 20
#define PTS 4096                       // 64*64 spatial points per (b,c) slab

typedef float f32x4 __attribute__((ext_vector_type(4)));

// Inline-asm global load: volatile keeps program order (no sinking), distinct
// "=v" outputs force all results live -> 14 loads genuinely outstanding.
// SGPR base + 32-bit voffset + imm offset minimizes address VGPRs.
#define GL(dst, base, voff, imm) \
    asm volatile("global_load_dwordx4 %0, %1, %2 offset:" #imm \
                 : "=v"(dst) : "v"(voff), "s"(base))

// Kernel 1: half-slab masked weighted reduction. grid = B*20*2 blocks,
// 256 threads; block handles 512 float4 of dis/mask space (2 groups of 256).
__global__ __launch_bounds__(256, 1) void vote_reduce(
    const float* __restrict__ fv, const float* __restrict__ fd,
    const float* __restrict__ bv, const float* __restrict__ bd,
    const float* __restrict__ mk, float* __restrict__ sums)
{
    const int bid  = blockIdx.x;
    const int slab = bid >> 1;               // b*20 + c
    const int half = bid & 1;
    const int tid  = threadIdx.x;

    // uniform slab bases -> SGPR pairs
    const float* fvp = fv + (size_t)slab * (PTS * 2);
    const float* bvp = bv + (size_t)slab * (PTS * 2);
    const float* fdp = fd + (size_t)slab * PTS;
    const float* bdp = bd + (size_t)slab * PTS;
    const float* mkp = mk + (size_t)slab * PTS;

    const int i0 = half * 512 + tid;         // float4 index, group 0
    const int i1 = i0 + 256;                 // group 1
    const unsigned off16_0 = (unsigned)i0 * 16u;   // dis/mask byte offset
    const unsigned off32_0 = (unsigned)i0 * 32u;   // vec byte offset
    const unsigned off16_1 = (unsigned)i1 * 16u;
    const unsigned off32_1 = (unsigned)i1 * 32u;

    f32x4 FVA0, FVB0, BVA0, BVB0, FD0, BD0, M0;
    f32x4 FVA1, FVB1, BVA1, BVB1, FD1, BD1, M1;

    // ---- issue all 14 loads (program order: group0's 7, then group1's 7) ----
    GL(FVA0, fvp, off32_0, 0);
    GL(FVB0, fvp, off32_0, 16);
    GL(BVA0, bvp, off32_0, 0);
    GL(BVB0, bvp, off32_0, 16);
    GL(FD0,  fdp, off16_0, 0);
    GL(BD0,  bdp, off16_0, 0);
    GL(M0,   mkp, off16_0, 0);
    GL(FVA1, fvp, off32_1, 0);
    GL(FVB1, fvp, off32_1, 16);
    GL(BVA1, bvp, off32_1, 0);
    GL(BVB1, bvp, off32_1, 16);
    GL(FD1,  fdp, off16_1, 0);
    GL(BD1,  bdp, off16_1, 0);
    GL(M1,   mkp, off16_1, 0);

    float fnx = 0.f, fny = 0.f, bnx = 0.f, bny = 0.f, den = 0.f;

#define CONSUME(FVA, FVB, BVA, BVB, FD4, BD4, M4, I)                         \
    {                                                                        \
        const float mm [4] = { M4.x,  M4.y,  M4.z,  M4.w  };                 \
        const float fdd[4] = { FD4.x, FD4.y, FD4.z, FD4.w };                 \
        const float bdd[4] = { BD4.x, BD4.y, BD4.z, BD4.w };                 \
        const float fvx[4] = { FVA.x, FVA.z, FVB.x, FVB.z };                 \
        const float fvy[4] = { FVA.y, FVA.w, FVB.y, FVB.w };                 \
        const float bvx[4] = { BVA.x, BVA.z, BVB.x, BVB.z };                 \
        const float bvy[4] = { BVA.y, BVA.w, BVB.y, BVB.w };                 \
        const int p0 = (I) * 4;                                              \
        _Pragma("unroll")                                                    \
        for (int q = 0; q < 4; ++q) {                                        \
            const int p  = p0 + q;                                           \
            const float x = (float)(p >> 6);   /* locs[...,0] = x */         \
            const float y = (float)(p & 63);   /* locs[...,1] = y */         \
            const float m = mm[q];                                           \
            fnx += m * (fvx[q] * fdd[q] * 64.f + x);                         \
            fny += m * (fvy[q] * fdd[q] * 64.f + y);                         \
            bnx += m * (bvx[q] * bdd[q] * 64.f + x);                         \
            bny += m * (bvy[q] * bdd[q] * 64.f + y);                         \
            den += m;                                                        \
        }                                                                    \
    }

    // group 0 ready when 7 newest (group 1) may still be in flight
    asm volatile("s_waitcnt vmcnt(7)" ::: "memory");
    __builtin_amdgcn_sched_barrier(0);
    CONSUME(FVA0, FVB0, BVA0, BVB0, FD0, BD0, M0, i0);

    asm volatile("s_waitcnt vmcnt(0)" ::: "memory");
    __builtin_amdgcn_sched_barrier(0);
    CONSUME(FVA1, FVB1, BVA1, BVB1, FD1, BD1, M1, i1);

    // ---- 64-lane wave butterfly reduce ----
    #pragma unroll
    for (int off = 32; off > 0; off >>= 1) {
        fnx += __shfl_down(fnx, off);
        fny += __shfl_down(fny, off);
        bnx += __shfl_down(bnx, off);
        bny += __shfl_down(bny, off);
        den += __shfl_down(den, off);
    }

    __shared__ float red[4][5];
    const int wave = tid >> 6;
    const int lane = tid & 63;
    if (lane == 0) {
        red[wave][0] = fnx; red[wave][1] = fny;
        red[wave][2] = bnx; red[wave][3] = bny;
        red[wave][4] = den;
    }
    __syncthreads();
    if (tid == 0) {
        float s0 = 0.f, s1 = 0.f, s2 = 0.f, s3 = 0.f, s4 = 0.f;
        #pragma unroll
        for (int w = 0; w < 4; ++w) {
            s0 += red[w][0]; s1 += red[w][1];
            s2 += red[w][2]; s3 += red[w][3];
            s4 += red[w][4];
        }
        float* o = sums + ((size_t)slab * 2 + half) * 5;
        o[0] = s0; o[1] = s1; o[2] = s2; o[3] = s3; o[4] = s4;
    }
}

// Kernel 2: per-batch finalize; merges the two half-slab partials.
__global__ __launch_bounds__(64) void combine(
    const float* __restrict__ sums, float* __restrict__ out, int B)
{
    const int b = blockIdx.x * blockDim.x + threadIdx.x;
    if (b >= B) return;

    float fsx[NCH], fsy[NCH], bsx[NCH], bsy[NCH];
    #pragma unroll
    for (int c = 0; c < NCH; ++c) {
        const float* s = sums + (size_t)(b * NCH + c) * 10;
        const float den = s[4] + s[9];
        const float inv = 1.f / (den + 1e-6f);
        fsx[c] = (s[0] + s[5]) * inv;
        fsy[c] = (s[1] + s[6]) * inv;
        bsx[c] = (s[2] + s[7]) * inv;
        bsy[c] = (s[3] + s[8]) * inv;
    }

    // wrist = mean of back predictions at channels 0,4,8,12,16
    const float k0x = 0.2f * (bsx[0] + bsx[4] + bsx[8] + bsx[12] + bsx[16]);
    const float k0y = 0.2f * (bsy[0] + bsy[4] + bsy[8] + bsy[12] + bsy[16]);

    float* o = out + (size_t)b * 42;         // 21 keypoints * 2
    o[0] = k0x * 4.f;
    o[1] = k0y * 4.f;

    #pragma unroll
    for (int c = 0; c < NCH; ++c) {
        const int j = c & 3;
        const int t = (c & ~3) + 4 - j;      // target keypoint 1..20
        float vx, vy;
        if (j == 3) {
            vx = fsx[c]; vy = fsy[c];
        } else {
            vx = 0.5f * (fsx[c] + bsx[c + 1]);
            vy = 0.5f * (fsy[c] + bsy[c + 1]);
        }
        o[t * 2]     = vx * 4.f;
        o[t * 2 + 1] = vy * 4.f;
    }
}

extern "C" void kernel_launch(void* const* d_in, const int* in_sizes, int n_in,
                              void* d_out, int out_size, void* d_ws, size_t ws_size,
                              hipStream_t stream) {
    const float* fv = (const float*)d_in[0];   // [B,20,64,64,2]
    const float* fd = (const float*)d_in[1];   // [B,20,64,64,1]
    const float* bv = (const float*)d_in[2];
    const float* bd = (const float*)d_in[3];
    const float* mk = (const float*)d_in[4];

    const int B = in_sizes[0] / (NCH * PTS * 2); // 256
    float* sums = (float*)d_ws;                  // [B*20][2][5] floats
    float* out  = (float*)d_out;

    vote_reduce<<<B * NCH * 2, 256, 0, stream>>>(fv, fd, bv, bd, mk, sums);
    combine<<<(B + 63) / 64, 64, 0, stream>>>(sums, out, B);
}

// Round 5
// 95.564 us; speedup vs baseline: 1.0967x; 1.0967x over previous
//
#include <hip/hip_runtime.h>

#define NCH 20
#define PTS 4096                       // 64*64 spatial points per (b,c) slab

typedef float f32x4 __attribute__((ext_vector_type(4)));

// Kernel 1: per-(b,c)-slab masked weighted reduction. grid = B*20, 256 thr.
// vec arrays (fv,bv: 335 MB total) are loaded NON-TEMPORALLY so they do not
// allocate in Infinity Cache; dis/mask (fd,bd,mk: 252 MB) stay cacheable and
// fit entirely in the 256 MB L3 across graph replays -> HBM streams vec while
// L3 serves dis/mask concurrently.
__global__ __launch_bounds__(256) void vote_reduce(
    const f32x4* __restrict__ fv, const f32x4* __restrict__ fd,
    const f32x4* __restrict__ bv, const f32x4* __restrict__ bd,
    const f32x4* __restrict__ mk, float* __restrict__ sums)
{
    const int slab = blockIdx.x;                 // b*20 + c
    const int tid  = threadIdx.x;

    const f32x4* fvp = fv + (size_t)slab * (PTS * 2 / 4);  // 2048 f32x4
    const f32x4* bvp = bv + (size_t)slab * (PTS * 2 / 4);
    const f32x4* fdp = fd + (size_t)slab * (PTS / 4);      // 1024 f32x4
    const f32x4* bdp = bd + (size_t)slab * (PTS / 4);
    const f32x4* mkp = mk + (size_t)slab * (PTS / 4);

    float fnx = 0.f, fny = 0.f, bnx = 0.f, bny = 0.f, den = 0.f;

    #pragma unroll
    for (int g = 0; g < 4; ++g) {
        const int i = g * 256 + tid;             // 0..1023; covers points 4i..4i+3
        const f32x4 fva = __builtin_nontemporal_load(&fvp[2 * i]);
        const f32x4 fvb = __builtin_nontemporal_load(&fvp[2 * i + 1]);
        const f32x4 bva = __builtin_nontemporal_load(&bvp[2 * i]);
        const f32x4 bvb = __builtin_nontemporal_load(&bvp[2 * i + 1]);
        const f32x4 fd4 = fdp[i];
        const f32x4 bd4 = bdp[i];
        const f32x4 m4  = mkp[i];

        const float mm [4] = { m4.x,  m4.y,  m4.z,  m4.w  };
        const float fdd[4] = { fd4.x, fd4.y, fd4.z, fd4.w };
        const float bdd[4] = { bd4.x, bd4.y, bd4.z, bd4.w };
        const float fvx[4] = { fva.x, fva.z, fvb.x, fvb.z };
        const float fvy[4] = { fva.y, fva.w, fvb.y, fvb.w };
        const float bvx[4] = { bva.x, bva.z, bvb.x, bvb.z };
        const float bvy[4] = { bva.y, bva.w, bvb.y, bvb.w };

        const int p0 = i * 4;
        #pragma unroll
        for (int q = 0; q < 4; ++q) {
            const int p  = p0 + q;
            const float x = (float)(p >> 6);     // locs[...,0] = x
            const float y = (float)(p & 63);     // locs[...,1] = y
            const float m = mm[q];
            fnx += m * (fvx[q] * fdd[q] * 64.f + x);
            fny += m * (fvy[q] * fdd[q] * 64.f + y);
            bnx += m * (bvx[q] * bdd[q] * 64.f + x);
            bny += m * (bvy[q] * bdd[q] * 64.f + y);
            den += m;
        }
    }

    // ---- 64-lane wave butterfly reduce ----
    #pragma unroll
    for (int off = 32; off > 0; off >>= 1) {
        fnx += __shfl_down(fnx, off);
        fny += __shfl_down(fny, off);
        bnx += __shfl_down(bnx, off);
        bny += __shfl_down(bny, off);
        den += __shfl_down(den, off);
    }

    __shared__ float red[4][5];
    const int wave = tid >> 6;
    const int lane = tid & 63;
    if (lane == 0) {
        red[wave][0] = fnx; red[wave][1] = fny;
        red[wave][2] = bnx; red[wave][3] = bny;
        red[wave][4] = den;
    }
    __syncthreads();
    if (tid == 0) {
        float s0 = 0.f, s1 = 0.f, s2 = 0.f, s3 = 0.f, s4 = 0.f;
        #pragma unroll
        for (int w = 0; w < 4; ++w) {
            s0 += red[w][0]; s1 += red[w][1];
            s2 += red[w][2]; s3 += red[w][3];
            s4 += red[w][4];
        }
        float* o = sums + (size_t)slab * 5;
        o[0] = s0; o[1] = s1; o[2] = s2; o[3] = s3; o[4] = s4;
    }
}

// Kernel 2: per-batch finalize, LDS-staged so the 20 B-record reads are
// coalesced f32x4 loads instead of 100 scattered scalar loads per thread.
// 4 blocks x 64 threads; each block stages 64 batches (6400 floats, 25.6 KB).
__global__ __launch_bounds__(64) void combine(
    const float* __restrict__ sums, float* __restrict__ out, int B)
{
    __shared__ float lds[64 * NCH * 5];          // 25,600 B
    const int tid = threadIdx.x;

    // coalesced stage: 1600 f32x4 per block, 25 per thread
    const f32x4* src = (const f32x4*)(sums + (size_t)blockIdx.x * (64 * NCH * 5));
    f32x4* dst = (f32x4*)lds;
    #pragma unroll
    for (int k = 0; k < 25; ++k)
        dst[k * 64 + tid] = src[k * 64 + tid];
    __syncthreads();

    const int b = blockIdx.x * 64 + tid;
    if (b >= B) return;

    const float* s0 = lds + (size_t)tid * (NCH * 5);
    float fsx[NCH], fsy[NCH], bsx[NCH], bsy[NCH];
    #pragma unroll
    for (int c = 0; c < NCH; ++c) {
        const float* s = s0 + c * 5;
        const float inv = 1.f / (s[4] + 1e-6f);
        fsx[c] = s[0] * inv; fsy[c] = s[1] * inv;
        bsx[c] = s[2] * inv; bsy[c] = s[3] * inv;
    }

    // wrist = mean of back predictions at channels 0,4,8,12,16
    const float k0x = 0.2f * (bsx[0] + bsx[4] + bsx[8] + bsx[12] + bsx[16]);
    const float k0y = 0.2f * (bsy[0] + bsy[4] + bsy[8] + bsy[12] + bsy[16]);

    float* o = out + (size_t)b * 42;             // 21 keypoints * 2
    o[0] = k0x * 4.f;
    o[1] = k0y * 4.f;

    #pragma unroll
    for (int c = 0; c < NCH; ++c) {
        const int j = c & 3;
        const int t = (c & ~3) + 4 - j;          // target keypoint 1..20
        float vx, vy;
        if (j == 3) {
            vx = fsx[c]; vy = fsy[c];
        } else {
            vx = 0.5f * (fsx[c] + bsx[c + 1]);
            vy = 0.5f * (fsy[c] + bsy[c + 1]);
        }
        o[t * 2]     = vx * 4.f;
        o[t * 2 + 1] = vy * 4.f;
    }
}

extern "C" void kernel_launch(void* const* d_in, const int* in_sizes, int n_in,
                              void* d_out, int out_size, void* d_ws, size_t ws_size,
                              hipStream_t stream) {
    const f32x4* fv = (const f32x4*)d_in[0];     // [B,20,64,64,2]
    const f32x4* fd = (const f32x4*)d_in[1];     // [B,20,64,64,1]
    const f32x4* bv = (const f32x4*)d_in[2];
    const f32x4* bd = (const f32x4*)d_in[3];
    const f32x4* mk = (const f32x4*)d_in[4];

    const int B = in_sizes[0] / (NCH * PTS * 2); // 256
    float* sums = (float*)d_ws;                  // [B*20][5] floats
    float* out  = (float*)d_out;

    vote_reduce<<<B * NCH, 256, 0, stream>>>(fv, fd, bv, bd, mk, sums);
    combine<<<(B + 63) / 64, 64, 0, stream>>>(sums, out, B);
}